// Round 11
// baseline (1267.110 us; speedup 1.0000x reference)
//
#include <hip/hip_runtime.h>

#define N_NODES 50000
#define N_EDGES 600000
#define DIM 128
#define NGRAPH 128
#define NLAYER 4
#define BN_EPS 1e-5f
#define SCAN_BLK 1024

#define EN_BLOCKS 3125    // N/16 nodes per block
#define WT_BLOCKS 512     // 2*L*D*D/256
#define HB_BLOCKS 2344    // ceil(E/256)

using short8  = __attribute__((ext_vector_type(8))) short;
using float4v = __attribute__((ext_vector_type(4))) float;

__device__ __forceinline__ float bf2f(unsigned short u) {
    union { unsigned int i; float f; } c; c.i = ((unsigned int)u) << 16; return c.f;
}
__device__ __forceinline__ unsigned short f2bf(float f) {
    union { float f; unsigned int i; } c; c.f = f;
    unsigned int x = c.i;
    return (unsigned short)((x + 0x7fffu + ((x >> 16) & 1u)) >> 16);
}

// ---------------- fused pre-pass: encode | weight-transpose | degree-histogram ----------------
__global__ void fused_pre_kernel(const int* __restrict__ feat_id,
                                 const float* __restrict__ rwse,
                                 const int* __restrict__ indeg,
                                 const float* __restrict__ value_W,
                                 const float* __restrict__ value_b,
                                 const float* __restrict__ rwse_W,
                                 const float* __restrict__ rwse_b,
                                 const float* __restrict__ deg_emb,
                                 unsigned short* __restrict__ hout,
                                 const float* __restrict__ W1,
                                 const float* __restrict__ W2,
                                 unsigned short* __restrict__ w1t,
                                 unsigned short* __restrict__ w2t,
                                 const int* __restrict__ dst,
                                 int* __restrict__ cnt)
{
    int b = blockIdx.x;
    if (b < EN_BLOCKS) {
        __shared__ float srw[16][16];
        __shared__ int   sfid[16], sdeg[16];
        const int t = threadIdx.x;
        const int base = b * 16;
        srw[t >> 4][t & 15] = rwse[(size_t)base * 16 + t];
        if (t < 16) sfid[t] = feat_id[base + t] & 127;
        else if (t < 32) {
            int dg = indeg[base + t - 16];
            sdeg[t - 16] = dg < 0 ? 0 : (dg > 1000 ? 1000 : dg);
        }
        const int d = t & 127, half = t >> 7;
        float wk[16];
#pragma unroll
        for (int k = 0; k < 16; ++k) wk[k] = rwse_W[k * DIM + d];
        float vb = value_b[d] + rwse_b[d];
        __syncthreads();
#pragma unroll
        for (int nn = 0; nn < 8; ++nn) {
            int nl = half * 8 + nn;
            int node = base + nl;
            float v = value_W[sfid[nl] * DIM + d] + vb + deg_emb[sdeg[nl] * DIM + d];
            float acc = 0.f;
#pragma unroll
            for (int k = 0; k < 16; ++k) acc += srw[nl][k] * wk[k];
            hout[(size_t)node * DIM + d] = f2bf(v + acc);
        }
    } else if (b < EN_BLOCKS + WT_BLOCKS) {
        int idx = (b - EN_BLOCKS) * 256 + threadIdx.x;
        int i = idx & (DIM * DIM - 1);
        int l = (idx >> 14) & 3;
        int is2 = idx >= NLAYER * DIM * DIM;
        int n = i >> 7, k = i & 127;
        const float* W = (is2 ? W2 : W1) + l * DIM * DIM;
        unsigned short v = f2bf(W[k * DIM + n]);
        (is2 ? w2t : w1t)[l * DIM * DIM + n * DIM + k] = v;
    } else {
        int e = (b - EN_BLOCKS - WT_BLOCKS) * 256 + threadIdx.x;
        if (e < N_EDGES) atomicAdd(&cnt[dst[e]], 1);
    }
}

// ---------------- CSR build ----------------
__global__ void scanA_kernel(const int* __restrict__ cnt, int* __restrict__ rp, int* __restrict__ bsum) {
    __shared__ int sc[SCAN_BLK];
    int t = threadIdx.x, i = blockIdx.x * SCAN_BLK + t;
    int v = (i < N_NODES) ? cnt[i] : 0;
    sc[t] = v; __syncthreads();
    for (int off = 1; off < SCAN_BLK; off <<= 1) {
        int add = (t >= off) ? sc[t - off] : 0;
        __syncthreads();
        sc[t] += add;
        __syncthreads();
    }
    if (i < N_NODES) rp[i] = sc[t] - v;
    if (t == SCAN_BLK - 1) bsum[blockIdx.x] = sc[t];
}

__global__ void scan_fixup_kernel(int* __restrict__ rp, const int* __restrict__ bsum,
                                  int* __restrict__ cur, int nsb) {
    __shared__ int sbx[64];
    int t = threadIdx.x;
    if (t < 64) {
        int v = (t < nsb) ? bsum[t] : 0;
        int orig = v;
        for (int off = 1; off < 64; off <<= 1) {
            int y = __shfl_up(v, off, 64);
            if (t >= off) v += y;
        }
        sbx[t] = v - orig;
    }
    __syncthreads();
    int i = blockIdx.x * 256 + t;
    if (i < N_NODES) { int v = rp[i] + sbx[i >> 10]; rp[i] = v; cur[i] = v; }
    else if (i == N_NODES) rp[i] = N_EDGES;
}

__global__ void scatter_kernel(const int* __restrict__ src, const int* __restrict__ dst,
                               int* __restrict__ cur, int* __restrict__ esrc) {
    int e = blockIdx.x * blockDim.x + threadIdx.x;
    if (e < N_EDGES) {
        int pos = atomicAdd(&cur[dst[e]], 1);
        esrc[pos] = src[e];
    }
}

// ---------------- fused layer v4: 4-node interleaved gather (4 row loads in flight) ----------------
// Block = 256 thr / 16 nodes. Wave w owns nodes w*4..w*4+3; 16-lane group fg handles every
// 4th edge of each node. All 4 nodes' edge lists are walked in ONE loop with 4 independent
// accumulators -> 4 row gathers + 4 index prefetches in flight. MLP: wave w owns cols w*32..+31.
__global__ void __launch_bounds__(256, 6) layer_kernel(
    const unsigned short* __restrict__ hin,
    const int* __restrict__ rp,
    const int* __restrict__ esrc,
    const unsigned short* __restrict__ w1t,
    const unsigned short* __restrict__ w2t,
    const float* __restrict__ b1, const float* __restrict__ b2,
    const float* __restrict__ gam, const float* __restrict__ bet,
    const float* __restrict__ mean, const float* __restrict__ var,
    unsigned short* __restrict__ hout, float* __restrict__ fout, int last)
{
    __shared__ unsigned short sA[16 * DIM];   // 4 KB gather/A tile
    __shared__ unsigned short sM[16 * DIM];   // 4 KB mid tile
    __shared__ int sRp[17];
    const int tid = threadIdx.x;
    const int wave = tid >> 6, lane = tid & 63;
    const int fr = lane & 15, fg = lane >> 4;
    const int base = blockIdx.x * 16;         // grid 3125 * 16 == N exactly, no tail

    if (tid < 17) sRp[tid] = rp[base + tid];

    // self-row of node (wave*4+fg), one parallel round across the 4 groups
    const int selfrow = wave * 4 + fg;
    uint4 selfv = *(const uint4*)(hin + (size_t)(base + selfrow) * DIM + fr * 8);

    __syncthreads();   // sRp ready

    int e_[4], e1_[4], sn_[4];
#pragma unroll
    for (int j = 0; j < 4; ++j) {
        int row = wave * 4 + j;
        e_[j]  = sRp[row] + fg;
        e1_[j] = sRp[row + 1];
        sn_[j] = (e_[j] < e1_[j]) ? esrc[e_[j]] : 0;
    }

    float a[4][8];
#pragma unroll
    for (int j = 0; j < 4; ++j)
#pragma unroll
        for (int i = 0; i < 8; ++i) a[j][i] = 0.f;

    // interleaved walk: per iteration, up to 4 independent 16B row loads in flight
    while (true) {
        bool act0 = e_[0] < e1_[0], act1 = e_[1] < e1_[1];
        bool act2 = e_[2] < e1_[2], act3 = e_[3] < e1_[3];
        if (!__any(act0 | act1 | act2 | act3)) break;
        uint4 v0, v1, v2, v3;
        if (act0) v0 = *(const uint4*)(hin + (size_t)sn_[0] * DIM + fr * 8);
        if (act1) v1 = *(const uint4*)(hin + (size_t)sn_[1] * DIM + fr * 8);
        if (act2) v2 = *(const uint4*)(hin + (size_t)sn_[2] * DIM + fr * 8);
        if (act3) v3 = *(const uint4*)(hin + (size_t)sn_[3] * DIM + fr * 8);
        // prefetch next indices (independent of the row loads above)
        if (act0) { e_[0] += 4; sn_[0] = (e_[0] < e1_[0]) ? esrc[e_[0]] : 0; }
        if (act1) { e_[1] += 4; sn_[1] = (e_[1] < e1_[1]) ? esrc[e_[1]] : 0; }
        if (act2) { e_[2] += 4; sn_[2] = (e_[2] < e1_[2]) ? esrc[e_[2]] : 0; }
        if (act3) { e_[3] += 4; sn_[3] = (e_[3] < e1_[3]) ? esrc[e_[3]] : 0; }
        if (act0) {
            a[0][0] += bf2f((unsigned short)(v0.x & 0xffff)); a[0][1] += bf2f((unsigned short)(v0.x >> 16));
            a[0][2] += bf2f((unsigned short)(v0.y & 0xffff)); a[0][3] += bf2f((unsigned short)(v0.y >> 16));
            a[0][4] += bf2f((unsigned short)(v0.z & 0xffff)); a[0][5] += bf2f((unsigned short)(v0.z >> 16));
            a[0][6] += bf2f((unsigned short)(v0.w & 0xffff)); a[0][7] += bf2f((unsigned short)(v0.w >> 16));
        }
        if (act1) {
            a[1][0] += bf2f((unsigned short)(v1.x & 0xffff)); a[1][1] += bf2f((unsigned short)(v1.x >> 16));
            a[1][2] += bf2f((unsigned short)(v1.y & 0xffff)); a[1][3] += bf2f((unsigned short)(v1.y >> 16));
            a[1][4] += bf2f((unsigned short)(v1.z & 0xffff)); a[1][5] += bf2f((unsigned short)(v1.z >> 16));
            a[1][6] += bf2f((unsigned short)(v1.w & 0xffff)); a[1][7] += bf2f((unsigned short)(v1.w >> 16));
        }
        if (act2) {
            a[2][0] += bf2f((unsigned short)(v2.x & 0xffff)); a[2][1] += bf2f((unsigned short)(v2.x >> 16));
            a[2][2] += bf2f((unsigned short)(v2.y & 0xffff)); a[2][3] += bf2f((unsigned short)(v2.y >> 16));
            a[2][4] += bf2f((unsigned short)(v2.z & 0xffff)); a[2][5] += bf2f((unsigned short)(v2.z >> 16));
            a[2][6] += bf2f((unsigned short)(v2.w & 0xffff)); a[2][7] += bf2f((unsigned short)(v2.w >> 16));
        }
        if (act3) {
            a[3][0] += bf2f((unsigned short)(v3.x & 0xffff)); a[3][1] += bf2f((unsigned short)(v3.x >> 16));
            a[3][2] += bf2f((unsigned short)(v3.y & 0xffff)); a[3][3] += bf2f((unsigned short)(v3.y >> 16));
            a[3][4] += bf2f((unsigned short)(v3.z & 0xffff)); a[3][5] += bf2f((unsigned short)(v3.z >> 16));
            a[3][6] += bf2f((unsigned short)(v3.w & 0xffff)); a[3][7] += bf2f((unsigned short)(v3.w >> 16));
        }
    }

#pragma unroll
    for (int j = 0; j < 4; ++j) {
#pragma unroll
        for (int i = 0; i < 8; ++i) {
            a[j][i] += __shfl_xor(a[j][i], 16, 64);
            a[j][i] += __shfl_xor(a[j][i], 32, 64);
        }
        if (fg == j) {   // group j holds node j's self row in regs; all its lanes have the sum
            float s0 = a[j][0] + bf2f((unsigned short)(selfv.x & 0xffff));
            float s1 = a[j][1] + bf2f((unsigned short)(selfv.x >> 16));
            float s2 = a[j][2] + bf2f((unsigned short)(selfv.y & 0xffff));
            float s3 = a[j][3] + bf2f((unsigned short)(selfv.y >> 16));
            float s4 = a[j][4] + bf2f((unsigned short)(selfv.z & 0xffff));
            float s5 = a[j][5] + bf2f((unsigned short)(selfv.z >> 16));
            float s6 = a[j][6] + bf2f((unsigned short)(selfv.w & 0xffff));
            float s7 = a[j][7] + bf2f((unsigned short)(selfv.w >> 16));
            uint4 o;
            o.x = (unsigned int)f2bf(s0) | ((unsigned int)f2bf(s1) << 16);
            o.y = (unsigned int)f2bf(s2) | ((unsigned int)f2bf(s3) << 16);
            o.z = (unsigned int)f2bf(s4) | ((unsigned int)f2bf(s5) << 16);
            o.w = (unsigned int)f2bf(s6) | ((unsigned int)f2bf(s7) << 16);
            int row = wave * 4 + j;
            int byte = row * 256 + fr * 16; byte ^= (row & 7) << 4;
            *(uint4*)((char*)sA + byte) = o;
        }
    }
    __syncthreads();

    // ---- GEMM1: A = sA rows 0..15 (full K), B = w1t cols wave*32..+31 (L1-hot) ----
    short8 a0, a1, a2, a3;
    {
        int sw = (fr & 7) << 4;
        a0 = *(const short8*)((char*)sA + ((fr * 256 + (0  + fg * 8) * 2) ^ sw));
        a1 = *(const short8*)((char*)sA + ((fr * 256 + (32 + fg * 8) * 2) ^ sw));
        a2 = *(const short8*)((char*)sA + ((fr * 256 + (64 + fg * 8) * 2) ^ sw));
        a3 = *(const short8*)((char*)sA + ((fr * 256 + (96 + fg * 8) * 2) ^ sw));
    }

    float4v acc[2];
    acc[0] = (float4v){0.f, 0.f, 0.f, 0.f};
    acc[1] = (float4v){0.f, 0.f, 0.f, 0.f};

    const unsigned short* bp1 = w1t + (wave * 32 + fr) * DIM + fg * 8;
#pragma unroll
    for (int nb = 0; nb < 2; ++nb) {
        const unsigned short* bb = bp1 + nb * 16 * DIM;
        short8 b0 = *(const short8*)(bb);
        short8 b1v = *(const short8*)(bb + 32);
        short8 b2v = *(const short8*)(bb + 64);
        short8 b3v = *(const short8*)(bb + 96);
        acc[nb] = __builtin_amdgcn_mfma_f32_16x16x32_bf16(a0, b0, acc[nb], 0, 0, 0);
        acc[nb] = __builtin_amdgcn_mfma_f32_16x16x32_bf16(a1, b1v, acc[nb], 0, 0, 0);
        acc[nb] = __builtin_amdgcn_mfma_f32_16x16x32_bf16(a2, b2v, acc[nb], 0, 0, 0);
        acc[nb] = __builtin_amdgcn_mfma_f32_16x16x32_bf16(a3, b3v, acc[nb], 0, 0, 0);
    }

    // ---- mid: bias + relu -> bf16 into sM (wave's 32-col slice) ----
#pragma unroll
    for (int nb = 0; nb < 2; ++nb) {
        int col = wave * 32 + nb * 16 + fr;
        float bias = b1[col];
#pragma unroll
        for (int r = 0; r < 4; ++r) {
            int row = fg * 4 + r;
            float v = acc[nb][r] + bias;
            v = fmaxf(v, 0.f);
            int byte = row * 256 + col * 2; byte ^= (row & 7) << 4;
            *(unsigned short*)((char*)sM + byte) = f2bf(v);
        }
    }
    __syncthreads();

    // ---- GEMM2: A = sM rows 0..15 (full K), B = w2t cols wave*32..+31 ----
    short8 m0, m1, m2, m3;
    {
        int sw = (fr & 7) << 4;
        m0 = *(const short8*)((char*)sM + ((fr * 256 + (0  + fg * 8) * 2) ^ sw));
        m1 = *(const short8*)((char*)sM + ((fr * 256 + (32 + fg * 8) * 2) ^ sw));
        m2 = *(const short8*)((char*)sM + ((fr * 256 + (64 + fg * 8) * 2) ^ sw));
        m3 = *(const short8*)((char*)sM + ((fr * 256 + (96 + fg * 8) * 2) ^ sw));
    }

    float4v acc2[2];
    acc2[0] = (float4v){0.f, 0.f, 0.f, 0.f};
    acc2[1] = (float4v){0.f, 0.f, 0.f, 0.f};

    const unsigned short* bp2 = w2t + (wave * 32 + fr) * DIM + fg * 8;
#pragma unroll
    for (int nb = 0; nb < 2; ++nb) {
        const unsigned short* bb = bp2 + nb * 16 * DIM;
        short8 b0 = *(const short8*)(bb);
        short8 b1v = *(const short8*)(bb + 32);
        short8 b2v = *(const short8*)(bb + 64);
        short8 b3v = *(const short8*)(bb + 96);
        acc2[nb] = __builtin_amdgcn_mfma_f32_16x16x32_bf16(m0, b0, acc2[nb], 0, 0, 0);
        acc2[nb] = __builtin_amdgcn_mfma_f32_16x16x32_bf16(m1, b1v, acc2[nb], 0, 0, 0);
        acc2[nb] = __builtin_amdgcn_mfma_f32_16x16x32_bf16(m2, b2v, acc2[nb], 0, 0, 0);
        acc2[nb] = __builtin_amdgcn_mfma_f32_16x16x32_bf16(m3, b3v, acc2[nb], 0, 0, 0);
    }

    // ---- epilogue: +b2, BN, ReLU, store ----
#pragma unroll
    for (int nb = 0; nb < 2; ++nb) {
        int col = wave * 32 + nb * 16 + fr;
        float bias = b2[col];
        float iv = gam[col] * rsqrtf(var[col] + BN_EPS);
        float mn = mean[col], bt = bet[col];
#pragma unroll
        for (int r = 0; r < 4; ++r) {
            int node = base + fg * 4 + r;
            float v = acc2[nb][r] + bias;
            v = (v - mn) * iv + bt;
            v = fmaxf(v, 0.f);
            if (last) fout[(size_t)node * DIM + col] = v;
            else hout[(size_t)node * DIM + col] = f2bf(v);
        }
    }
}

// ---------------- pooling: 8 blocks/graph non-atomic partials, then combine+divide ----------------
__global__ void __launch_bounds__(256) pool_partial_kernel(const float* __restrict__ h,
                                                           const int* __restrict__ batch,
                                                           float* __restrict__ partial)
{
    __shared__ float sums[256];
    __shared__ int sb[2];
    int g = blockIdx.x >> 3, split = blockIdx.x & 7;
    if (threadIdx.x < 2) {
        int target = g + threadIdx.x;
        int lo = 0, hi = N_NODES;
        while (lo < hi) { int mid = (lo + hi) >> 1; if (batch[mid] < target) lo = mid + 1; else hi = mid; }
        sb[threadIdx.x] = lo;
    }
    __syncthreads();
    int lo = sb[0], hi = sb[1];
    int d = threadIdx.x & 127, half = threadIdx.x >> 7;
    float acc = 0.f;
    for (int n = lo + split * 2 + half; n < hi; n += 16) acc += h[(size_t)n * DIM + d];
    sums[threadIdx.x] = acc;
    __syncthreads();
    if (threadIdx.x < 128)
        partial[blockIdx.x * DIM + threadIdx.x] = sums[threadIdx.x] + sums[threadIdx.x + 128];
}

__global__ void pool_comb_kernel(const float* __restrict__ partial,
                                 const int* __restrict__ batch,
                                 float* __restrict__ out)
{
    __shared__ int sb[2];
    int g = blockIdx.x, t = threadIdx.x;
    if (t < 2) {
        int target = g + t;
        int lo = 0, hi = N_NODES;
        while (lo < hi) { int mid = (lo + hi) >> 1; if (batch[mid] < target) lo = mid + 1; else hi = mid; }
        sb[t] = lo;
    }
    __syncthreads();
    float s = 0.f;
#pragma unroll
    for (int sp = 0; sp < 8; ++sp) s += partial[(g * 8 + sp) * DIM + t];
    float c = (float)(sb[1] - sb[0]);
    out[g * DIM + t] = s / fmaxf(c, 1.f);
}

extern "C" void kernel_launch(void* const* d_in, const int* in_sizes, int n_in,
                              void* d_out, int out_size, void* d_ws, size_t ws_size,
                              hipStream_t stream)
{
    const int*   feat_id = (const int*)d_in[0];
    const int*   eidx    = (const int*)d_in[1];
    const int*   batch   = (const int*)d_in[2];
    const float* rwse    = (const float*)d_in[3];
    const int*   indeg   = (const int*)d_in[4];
    const float* value_W = (const float*)d_in[5];
    const float* value_b = (const float*)d_in[6];
    const float* rwse_W  = (const float*)d_in[7];
    const float* rwse_b  = (const float*)d_in[8];
    const float* deg_emb = (const float*)d_in[9];
    const float* W1      = (const float*)d_in[10];
    const float* b1      = (const float*)d_in[11];
    const float* W2      = (const float*)d_in[12];
    const float* b2      = (const float*)d_in[13];
    const float* gam     = (const float*)d_in[14];
    const float* bet     = (const float*)d_in[15];
    const float* mean    = (const float*)d_in[16];
    const float* var     = (const float*)d_in[17];

    const int* srcv = eidx;
    const int* dstv = eidx + N_EDGES;

    char* p = (char*)d_ws;
    auto alloc = [&](size_t bytes) { char* r = p; p += (bytes + 255) & ~(size_t)255; return r; };
    unsigned short* hA   = (unsigned short*)alloc((size_t)N_NODES * DIM * 2);
    unsigned short* hB   = (unsigned short*)alloc((size_t)N_NODES * DIM * 2);
    int* cnt  = (int*)alloc((size_t)N_NODES * 4);
    int* rp   = (int*)alloc((size_t)(N_NODES + 1) * 4);
    int* cur  = (int*)alloc((size_t)N_NODES * 4);
    int* bsum = (int*)alloc(64 * 4);
    int* esrc = (int*)alloc((size_t)N_EDGES * 4);
    unsigned short* w1t = (unsigned short*)alloc((size_t)NLAYER * DIM * DIM * 2);
    unsigned short* w2t = (unsigned short*)alloc((size_t)NLAYER * DIM * DIM * 2);
    float* partial = (float*)alloc((size_t)NGRAPH * 8 * DIM * 4);

    float* out = (float*)d_out;
    float* hf  = out + NGRAPH * DIM;   // h output region [N, D] f32

    hipMemsetAsync(cnt, 0, (size_t)N_NODES * 4, stream);
    fused_pre_kernel<<<EN_BLOCKS + WT_BLOCKS + HB_BLOCKS, 256, 0, stream>>>(
        feat_id, rwse, indeg, value_W, value_b, rwse_W, rwse_b, deg_emb, hA,
        W1, W2, w1t, w2t, dstv, cnt);
    int nsb = (N_NODES + SCAN_BLK - 1) / SCAN_BLK;   // 49
    scanA_kernel<<<nsb, SCAN_BLK, 0, stream>>>(cnt, rp, bsum);
    scan_fixup_kernel<<<(N_NODES + 1 + 255) / 256, 256, 0, stream>>>(rp, bsum, cur, nsb);
    scatter_kernel<<<(N_EDGES + 255) / 256, 256, 0, stream>>>(srcv, dstv, cur, esrc);

    const int nlb = N_NODES / 16;   // 3125, exact
    for (int l = 0; l < NLAYER; ++l) {
        const unsigned short* hi = (l & 1) ? hB : hA;
        unsigned short*       ho = (l & 1) ? hA : hB;
        layer_kernel<<<nlb, 256, 0, stream>>>(hi, rp, esrc,
            w1t + l * DIM * DIM, w2t + l * DIM * DIM,
            b1 + l * DIM, b2 + l * DIM, gam + l * DIM, bet + l * DIM,
            mean + l * DIM, var + l * DIM,
            ho, hf, (l == NLAYER - 1) ? 1 : 0);
    }
    pool_partial_kernel<<<NGRAPH * 8, 256, 0, stream>>>(hf, batch, partial);
    pool_comb_kernel<<<NGRAPH, DIM, 0, stream>>>(partial, batch, out);
}

// Round 12
// 390.300 us; speedup vs baseline: 3.2465x; 3.2465x over previous
//
#include <hip/hip_runtime.h>

#define N_NODES 50000
#define N_EDGES 600000
#define DIM 128
#define NGRAPH 128
#define NLAYER 4
#define BN_EPS 1e-5f
#define SCAN_BLK 1024

#define EN_BLOCKS 3125    // N/16 nodes per block
#define WT_BLOCKS 512     // 2*L*D*D/256
#define HB_BLOCKS 2344    // ceil(E/256)

using short8  = __attribute__((ext_vector_type(8))) short;
using float4v = __attribute__((ext_vector_type(4))) float;

__device__ __forceinline__ float bf2f(unsigned short u) {
    union { unsigned int i; float f; } c; c.i = ((unsigned int)u) << 16; return c.f;
}
__device__ __forceinline__ unsigned short f2bf(float f) {
    union { float f; unsigned int i; } c; c.f = f;
    unsigned int x = c.i;
    return (unsigned short)((x + 0x7fffu + ((x >> 16) & 1u)) >> 16);
}

// ---------------- fused pre-pass: encode | weight-transpose | degree-histogram ----------------
__global__ void fused_pre_kernel(const int* __restrict__ feat_id,
                                 const float* __restrict__ rwse,
                                 const int* __restrict__ indeg,
                                 const float* __restrict__ value_W,
                                 const float* __restrict__ value_b,
                                 const float* __restrict__ rwse_W,
                                 const float* __restrict__ rwse_b,
                                 const float* __restrict__ deg_emb,
                                 unsigned short* __restrict__ hout,
                                 const float* __restrict__ W1,
                                 const float* __restrict__ W2,
                                 unsigned short* __restrict__ w1t,
                                 unsigned short* __restrict__ w2t,
                                 const int* __restrict__ dst,
                                 int* __restrict__ cnt)
{
    int b = blockIdx.x;
    if (b < EN_BLOCKS) {
        __shared__ float srw[16][16];
        __shared__ int   sfid[16], sdeg[16];
        const int t = threadIdx.x;
        const int base = b * 16;
        srw[t >> 4][t & 15] = rwse[(size_t)base * 16 + t];
        if (t < 16) sfid[t] = feat_id[base + t] & 127;
        else if (t < 32) {
            int dg = indeg[base + t - 16];
            sdeg[t - 16] = dg < 0 ? 0 : (dg > 1000 ? 1000 : dg);
        }
        const int d = t & 127, half = t >> 7;
        float wk[16];
#pragma unroll
        for (int k = 0; k < 16; ++k) wk[k] = rwse_W[k * DIM + d];
        float vb = value_b[d] + rwse_b[d];
        __syncthreads();
#pragma unroll
        for (int nn = 0; nn < 8; ++nn) {
            int nl = half * 8 + nn;
            int node = base + nl;
            float v = value_W[sfid[nl] * DIM + d] + vb + deg_emb[sdeg[nl] * DIM + d];
            float acc = 0.f;
#pragma unroll
            for (int k = 0; k < 16; ++k) acc += srw[nl][k] * wk[k];
            hout[(size_t)node * DIM + d] = f2bf(v + acc);
        }
    } else if (b < EN_BLOCKS + WT_BLOCKS) {
        int idx = (b - EN_BLOCKS) * 256 + threadIdx.x;
        int i = idx & (DIM * DIM - 1);
        int l = (idx >> 14) & 3;
        int is2 = idx >= NLAYER * DIM * DIM;
        int n = i >> 7, k = i & 127;
        const float* W = (is2 ? W2 : W1) + l * DIM * DIM;
        unsigned short v = f2bf(W[k * DIM + n]);
        (is2 ? w2t : w1t)[l * DIM * DIM + n * DIM + k] = v;
    } else {
        int e = (b - EN_BLOCKS - WT_BLOCKS) * 256 + threadIdx.x;
        if (e < N_EDGES) atomicAdd(&cnt[dst[e]], 1);
    }
}

// ---------------- CSR build ----------------
__global__ void scanA_kernel(const int* __restrict__ cnt, int* __restrict__ rp, int* __restrict__ bsum) {
    __shared__ int sc[SCAN_BLK];
    int t = threadIdx.x, i = blockIdx.x * SCAN_BLK + t;
    int v = (i < N_NODES) ? cnt[i] : 0;
    sc[t] = v; __syncthreads();
    for (int off = 1; off < SCAN_BLK; off <<= 1) {
        int add = (t >= off) ? sc[t - off] : 0;
        __syncthreads();
        sc[t] += add;
        __syncthreads();
    }
    if (i < N_NODES) rp[i] = sc[t] - v;
    if (t == SCAN_BLK - 1) bsum[blockIdx.x] = sc[t];
}

__global__ void scan_fixup_kernel(int* __restrict__ rp, const int* __restrict__ bsum,
                                  int* __restrict__ cur, int nsb) {
    __shared__ int sbx[64];
    int t = threadIdx.x;
    if (t < 64) {
        int v = (t < nsb) ? bsum[t] : 0;
        int orig = v;
        for (int off = 1; off < 64; off <<= 1) {
            int y = __shfl_up(v, off, 64);
            if (t >= off) v += y;
        }
        sbx[t] = v - orig;
    }
    __syncthreads();
    int i = blockIdx.x * 256 + t;
    if (i < N_NODES) { int v = rp[i] + sbx[i >> 10]; rp[i] = v; cur[i] = v; }
    else if (i == N_NODES) rp[i] = N_EDGES;
}

__global__ void scatter_kernel(const int* __restrict__ src, const int* __restrict__ dst,
                               int* __restrict__ cur, int* __restrict__ esrc) {
    int e = blockIdx.x * blockDim.x + threadIdx.x;
    if (e < N_EDGES) {
        int pos = atomicAdd(&cur[dst[e]], 1);
        esrc[pos] = src[e];
    }
}

// ---------------- fused layer v5: 2-node pair-interleaved gather (register-budget safe) ----------
// Block = 256 thr / 16 nodes. Wave w owns nodes w*4..w*4+3, processed as 2 pairs; within a pair
// both nodes' edge walks interleave -> 2 independent row loads in flight. Inactive node's load
// is zero-filled and accumulated unconditionally (adds 0) to keep control flow flat.
__global__ void __launch_bounds__(256, 8) layer_kernel(
    const unsigned short* __restrict__ hin,
    const int* __restrict__ rp,
    const int* __restrict__ esrc,
    const unsigned short* __restrict__ w1t,
    const unsigned short* __restrict__ w2t,
    const float* __restrict__ b1, const float* __restrict__ b2,
    const float* __restrict__ gam, const float* __restrict__ bet,
    const float* __restrict__ mean, const float* __restrict__ var,
    unsigned short* __restrict__ hout, float* __restrict__ fout, int last)
{
    __shared__ unsigned short sA[16 * DIM];   // 4 KB gather/A tile
    __shared__ unsigned short sM[16 * DIM];   // 4 KB mid tile
    __shared__ int sRp[17];
    const int tid = threadIdx.x;
    const int wave = tid >> 6, lane = tid & 63;
    const int fr = lane & 15, fg = lane >> 4;
    const int base = blockIdx.x * 16;         // grid 3125 * 16 == N exactly, no tail

    if (tid < 17) sRp[tid] = rp[base + tid];

    // self-row of node (wave*4+fg), one parallel round across the 4 groups
    const int selfrow = wave * 4 + fg;
    uint4 selfv = *(const uint4*)(hin + (size_t)(base + selfrow) * DIM + fr * 8);

    __syncthreads();   // sRp ready

#pragma unroll
    for (int jp = 0; jp < 2; ++jp) {
        const int j0 = jp * 2, j1 = jp * 2 + 1;
        const int row0 = wave * 4 + j0, row1 = wave * 4 + j1;

        float a0v[8], a1v[8];
#pragma unroll
        for (int i = 0; i < 8; ++i) { a0v[i] = 0.f; a1v[i] = 0.f; }

        int e0 = sRp[row0] + fg, e0e = sRp[row0 + 1];
        int e1 = sRp[row1] + fg, e1e = sRp[row1 + 1];
        bool act0 = e0 < e0e, act1 = e1 < e1e;
        int s0 = act0 ? esrc[e0] : 0;
        int s1 = act1 ? esrc[e1] : 0;

        while (__any(act0 || act1)) {
            uint4 v0 = (uint4){0u, 0u, 0u, 0u};
            uint4 v1 = (uint4){0u, 0u, 0u, 0u};
            if (act0) v0 = *(const uint4*)(hin + (size_t)s0 * DIM + fr * 8);
            if (act1) v1 = *(const uint4*)(hin + (size_t)s1 * DIM + fr * 8);
            if (act0) { e0 += 4; act0 = e0 < e0e; s0 = act0 ? esrc[e0] : 0; }
            if (act1) { e1 += 4; act1 = e1 < e1e; s1 = act1 ? esrc[e1] : 0; }
            // unconditional accumulate: inactive side adds bf2f(0) == 0
            a0v[0] += bf2f((unsigned short)(v0.x & 0xffff)); a0v[1] += bf2f((unsigned short)(v0.x >> 16));
            a0v[2] += bf2f((unsigned short)(v0.y & 0xffff)); a0v[3] += bf2f((unsigned short)(v0.y >> 16));
            a0v[4] += bf2f((unsigned short)(v0.z & 0xffff)); a0v[5] += bf2f((unsigned short)(v0.z >> 16));
            a0v[6] += bf2f((unsigned short)(v0.w & 0xffff)); a0v[7] += bf2f((unsigned short)(v0.w >> 16));
            a1v[0] += bf2f((unsigned short)(v1.x & 0xffff)); a1v[1] += bf2f((unsigned short)(v1.x >> 16));
            a1v[2] += bf2f((unsigned short)(v1.y & 0xffff)); a1v[3] += bf2f((unsigned short)(v1.y >> 16));
            a1v[4] += bf2f((unsigned short)(v1.z & 0xffff)); a1v[5] += bf2f((unsigned short)(v1.z >> 16));
            a1v[6] += bf2f((unsigned short)(v1.w & 0xffff)); a1v[7] += bf2f((unsigned short)(v1.w >> 16));
        }

#pragma unroll
        for (int i = 0; i < 8; ++i) {
            a0v[i] += __shfl_xor(a0v[i], 16, 64);
            a0v[i] += __shfl_xor(a0v[i], 32, 64);
            a1v[i] += __shfl_xor(a1v[i], 16, 64);
            a1v[i] += __shfl_xor(a1v[i], 32, 64);
        }
        if (fg == j0) {   // group j0 holds node row0's self row; all its lanes have the sum
            float s0f = a0v[0] + bf2f((unsigned short)(selfv.x & 0xffff));
            float s1f = a0v[1] + bf2f((unsigned short)(selfv.x >> 16));
            float s2f = a0v[2] + bf2f((unsigned short)(selfv.y & 0xffff));
            float s3f = a0v[3] + bf2f((unsigned short)(selfv.y >> 16));
            float s4f = a0v[4] + bf2f((unsigned short)(selfv.z & 0xffff));
            float s5f = a0v[5] + bf2f((unsigned short)(selfv.z >> 16));
            float s6f = a0v[6] + bf2f((unsigned short)(selfv.w & 0xffff));
            float s7f = a0v[7] + bf2f((unsigned short)(selfv.w >> 16));
            uint4 o;
            o.x = (unsigned int)f2bf(s0f) | ((unsigned int)f2bf(s1f) << 16);
            o.y = (unsigned int)f2bf(s2f) | ((unsigned int)f2bf(s3f) << 16);
            o.z = (unsigned int)f2bf(s4f) | ((unsigned int)f2bf(s5f) << 16);
            o.w = (unsigned int)f2bf(s6f) | ((unsigned int)f2bf(s7f) << 16);
            int byte = row0 * 256 + fr * 16; byte ^= (row0 & 7) << 4;
            *(uint4*)((char*)sA + byte) = o;
        }
        if (fg == j1) {
            float s0f = a1v[0] + bf2f((unsigned short)(selfv.x & 0xffff));
            float s1f = a1v[1] + bf2f((unsigned short)(selfv.x >> 16));
            float s2f = a1v[2] + bf2f((unsigned short)(selfv.y & 0xffff));
            float s3f = a1v[3] + bf2f((unsigned short)(selfv.y >> 16));
            float s4f = a1v[4] + bf2f((unsigned short)(selfv.z & 0xffff));
            float s5f = a1v[5] + bf2f((unsigned short)(selfv.z >> 16));
            float s6f = a1v[6] + bf2f((unsigned short)(selfv.w & 0xffff));
            float s7f = a1v[7] + bf2f((unsigned short)(selfv.w >> 16));
            uint4 o;
            o.x = (unsigned int)f2bf(s0f) | ((unsigned int)f2bf(s1f) << 16);
            o.y = (unsigned int)f2bf(s2f) | ((unsigned int)f2bf(s3f) << 16);
            o.z = (unsigned int)f2bf(s4f) | ((unsigned int)f2bf(s5f) << 16);
            o.w = (unsigned int)f2bf(s6f) | ((unsigned int)f2bf(s7f) << 16);
            int byte = row1 * 256 + fr * 16; byte ^= (row1 & 7) << 4;
            *(uint4*)((char*)sA + byte) = o;
        }
    }
    __syncthreads();

    // ---- GEMM1: A = sA rows 0..15 (full K), B = w1t cols wave*32..+31 (L1-hot) ----
    short8 a0, a1, a2, a3;
    {
        int sw = (fr & 7) << 4;
        a0 = *(const short8*)((char*)sA + ((fr * 256 + (0  + fg * 8) * 2) ^ sw));
        a1 = *(const short8*)((char*)sA + ((fr * 256 + (32 + fg * 8) * 2) ^ sw));
        a2 = *(const short8*)((char*)sA + ((fr * 256 + (64 + fg * 8) * 2) ^ sw));
        a3 = *(const short8*)((char*)sA + ((fr * 256 + (96 + fg * 8) * 2) ^ sw));
    }

    float4v acc[2];
    acc[0] = (float4v){0.f, 0.f, 0.f, 0.f};
    acc[1] = (float4v){0.f, 0.f, 0.f, 0.f};

    const unsigned short* bp1 = w1t + (wave * 32 + fr) * DIM + fg * 8;
#pragma unroll
    for (int nb = 0; nb < 2; ++nb) {
        const unsigned short* bb = bp1 + nb * 16 * DIM;
        short8 b0 = *(const short8*)(bb);
        short8 b1v = *(const short8*)(bb + 32);
        short8 b2v = *(const short8*)(bb + 64);
        short8 b3v = *(const short8*)(bb + 96);
        acc[nb] = __builtin_amdgcn_mfma_f32_16x16x32_bf16(a0, b0, acc[nb], 0, 0, 0);
        acc[nb] = __builtin_amdgcn_mfma_f32_16x16x32_bf16(a1, b1v, acc[nb], 0, 0, 0);
        acc[nb] = __builtin_amdgcn_mfma_f32_16x16x32_bf16(a2, b2v, acc[nb], 0, 0, 0);
        acc[nb] = __builtin_amdgcn_mfma_f32_16x16x32_bf16(a3, b3v, acc[nb], 0, 0, 0);
    }

    // ---- mid: bias + relu -> bf16 into sM (wave's 32-col slice) ----
#pragma unroll
    for (int nb = 0; nb < 2; ++nb) {
        int col = wave * 32 + nb * 16 + fr;
        float bias = b1[col];
#pragma unroll
        for (int r = 0; r < 4; ++r) {
            int row = fg * 4 + r;
            float v = acc[nb][r] + bias;
            v = fmaxf(v, 0.f);
            int byte = row * 256 + col * 2; byte ^= (row & 7) << 4;
            *(unsigned short*)((char*)sM + byte) = f2bf(v);
        }
    }
    __syncthreads();

    // ---- GEMM2: A = sM rows 0..15 (full K), B = w2t cols wave*32..+31 ----
    short8 m0, m1, m2, m3;
    {
        int sw = (fr & 7) << 4;
        m0 = *(const short8*)((char*)sM + ((fr * 256 + (0  + fg * 8) * 2) ^ sw));
        m1 = *(const short8*)((char*)sM + ((fr * 256 + (32 + fg * 8) * 2) ^ sw));
        m2 = *(const short8*)((char*)sM + ((fr * 256 + (64 + fg * 8) * 2) ^ sw));
        m3 = *(const short8*)((char*)sM + ((fr * 256 + (96 + fg * 8) * 2) ^ sw));
    }

    float4v acc2[2];
    acc2[0] = (float4v){0.f, 0.f, 0.f, 0.f};
    acc2[1] = (float4v){0.f, 0.f, 0.f, 0.f};

    const unsigned short* bp2 = w2t + (wave * 32 + fr) * DIM + fg * 8;
#pragma unroll
    for (int nb = 0; nb < 2; ++nb) {
        const unsigned short* bb = bp2 + nb * 16 * DIM;
        short8 b0 = *(const short8*)(bb);
        short8 b1v = *(const short8*)(bb + 32);
        short8 b2v = *(const short8*)(bb + 64);
        short8 b3v = *(const short8*)(bb + 96);
        acc2[nb] = __builtin_amdgcn_mfma_f32_16x16x32_bf16(m0, b0, acc2[nb], 0, 0, 0);
        acc2[nb] = __builtin_amdgcn_mfma_f32_16x16x32_bf16(m1, b1v, acc2[nb], 0, 0, 0);
        acc2[nb] = __builtin_amdgcn_mfma_f32_16x16x32_bf16(m2, b2v, acc2[nb], 0, 0, 0);
        acc2[nb] = __builtin_amdgcn_mfma_f32_16x16x32_bf16(m3, b3v, acc2[nb], 0, 0, 0);
    }

    // ---- epilogue: +b2, BN, ReLU, store ----
#pragma unroll
    for (int nb = 0; nb < 2; ++nb) {
        int col = wave * 32 + nb * 16 + fr;
        float bias = b2[col];
        float iv = gam[col] * rsqrtf(var[col] + BN_EPS);
        float mn = mean[col], bt = bet[col];
#pragma unroll
        for (int r = 0; r < 4; ++r) {
            int node = base + fg * 4 + r;
            float v = acc2[nb][r] + bias;
            v = (v - mn) * iv + bt;
            v = fmaxf(v, 0.f);
            if (last) fout[(size_t)node * DIM + col] = v;
            else hout[(size_t)node * DIM + col] = f2bf(v);
        }
    }
}

// ---------------- pooling: 8 blocks/graph non-atomic partials, then combine+divide ----------------
__global__ void __launch_bounds__(256) pool_partial_kernel(const float* __restrict__ h,
                                                           const int* __restrict__ batch,
                                                           float* __restrict__ partial)
{
    __shared__ float sums[256];
    __shared__ int sb[2];
    int g = blockIdx.x >> 3, split = blockIdx.x & 7;
    if (threadIdx.x < 2) {
        int target = g + threadIdx.x;
        int lo = 0, hi = N_NODES;
        while (lo < hi) { int mid = (lo + hi) >> 1; if (batch[mid] < target) lo = mid + 1; else hi = mid; }
        sb[threadIdx.x] = lo;
    }
    __syncthreads();
    int lo = sb[0], hi = sb[1];
    int d = threadIdx.x & 127, half = threadIdx.x >> 7;
    float acc = 0.f;
    for (int n = lo + split * 2 + half; n < hi; n += 16) acc += h[(size_t)n * DIM + d];
    sums[threadIdx.x] = acc;
    __syncthreads();
    if (threadIdx.x < 128)
        partial[blockIdx.x * DIM + threadIdx.x] = sums[threadIdx.x] + sums[threadIdx.x + 128];
}

__global__ void pool_comb_kernel(const float* __restrict__ partial,
                                 const int* __restrict__ batch,
                                 float* __restrict__ out)
{
    __shared__ int sb[2];
    int g = blockIdx.x, t = threadIdx.x;
    if (t < 2) {
        int target = g + t;
        int lo = 0, hi = N_NODES;
        while (lo < hi) { int mid = (lo + hi) >> 1; if (batch[mid] < target) lo = mid + 1; else hi = mid; }
        sb[t] = lo;
    }
    __syncthreads();
    float s = 0.f;
#pragma unroll
    for (int sp = 0; sp < 8; ++sp) s += partial[(g * 8 + sp) * DIM + t];
    float c = (float)(sb[1] - sb[0]);
    out[g * DIM + t] = s / fmaxf(c, 1.f);
}

extern "C" void kernel_launch(void* const* d_in, const int* in_sizes, int n_in,
                              void* d_out, int out_size, void* d_ws, size_t ws_size,
                              hipStream_t stream)
{
    const int*   feat_id = (const int*)d_in[0];
    const int*   eidx    = (const int*)d_in[1];
    const int*   batch   = (const int*)d_in[2];
    const float* rwse    = (const float*)d_in[3];
    const int*   indeg   = (const int*)d_in[4];
    const float* value_W = (const float*)d_in[5];
    const float* value_b = (const float*)d_in[6];
    const float* rwse_W  = (const float*)d_in[7];
    const float* rwse_b  = (const float*)d_in[8];
    const float* deg_emb = (const float*)d_in[9];
    const float* W1      = (const float*)d_in[10];
    const float* b1      = (const float*)d_in[11];
    const float* W2      = (const float*)d_in[12];
    const float* b2      = (const float*)d_in[13];
    const float* gam     = (const float*)d_in[14];
    const float* bet     = (const float*)d_in[15];
    const float* mean    = (const float*)d_in[16];
    const float* var     = (const float*)d_in[17];

    const int* srcv = eidx;
    const int* dstv = eidx + N_EDGES;

    char* p = (char*)d_ws;
    auto alloc = [&](size_t bytes) { char* r = p; p += (bytes + 255) & ~(size_t)255; return r; };
    unsigned short* hA   = (unsigned short*)alloc((size_t)N_NODES * DIM * 2);
    unsigned short* hB   = (unsigned short*)alloc((size_t)N_NODES * DIM * 2);
    int* cnt  = (int*)alloc((size_t)N_NODES * 4);
    int* rp   = (int*)alloc((size_t)(N_NODES + 1) * 4);
    int* cur  = (int*)alloc((size_t)N_NODES * 4);
    int* bsum = (int*)alloc(64 * 4);
    int* esrc = (int*)alloc((size_t)N_EDGES * 4);
    unsigned short* w1t = (unsigned short*)alloc((size_t)NLAYER * DIM * DIM * 2);
    unsigned short* w2t = (unsigned short*)alloc((size_t)NLAYER * DIM * DIM * 2);
    float* partial = (float*)alloc((size_t)NGRAPH * 8 * DIM * 4);

    float* out = (float*)d_out;
    float* hf  = out + NGRAPH * DIM;   // h output region [N, D] f32

    hipMemsetAsync(cnt, 0, (size_t)N_NODES * 4, stream);
    fused_pre_kernel<<<EN_BLOCKS + WT_BLOCKS + HB_BLOCKS, 256, 0, stream>>>(
        feat_id, rwse, indeg, value_W, value_b, rwse_W, rwse_b, deg_emb, hA,
        W1, W2, w1t, w2t, dstv, cnt);
    int nsb = (N_NODES + SCAN_BLK - 1) / SCAN_BLK;   // 49
    scanA_kernel<<<nsb, SCAN_BLK, 0, stream>>>(cnt, rp, bsum);
    scan_fixup_kernel<<<(N_NODES + 1 + 255) / 256, 256, 0, stream>>>(rp, bsum, cur, nsb);
    scatter_kernel<<<(N_EDGES + 255) / 256, 256, 0, stream>>>(srcv, dstv, cur, esrc);

    const int nlb = N_NODES / 16;   // 3125, exact
    for (int l = 0; l < NLAYER; ++l) {
        const unsigned short* hi = (l & 1) ? hB : hA;
        unsigned short*       ho = (l & 1) ? hA : hB;
        layer_kernel<<<nlb, 256, 0, stream>>>(hi, rp, esrc,
            w1t + l * DIM * DIM, w2t + l * DIM * DIM,
            b1 + l * DIM, b2 + l * DIM, gam + l * DIM, bet + l * DIM,
            mean + l * DIM, var + l * DIM,
            ho, hf, (l == NLAYER - 1) ? 1 : 0);
    }
    pool_partial_kernel<<<NGRAPH * 8, 256, 0, stream>>>(hf, batch, partial);
    pool_comb_kernel<<<NGRAPH, DIM, 0, stream>>>(partial, batch, out);
}